// Round 8
// baseline (255.868 us; speedup 1.0000x reference)
//
#include <hip/hip_runtime.h>
#include <hip/hip_bf16.h>

#define D_MODEL 1024
#define D_STATE 16
#define D_CONV 4
#define D_INNER 2048
#define DT_RANK 128
#define BATCH 2
#define SEQLEN 1024
#define XCOLS 160     // DT_RANK + 2*D_STATE
#define NCHUNK 32
#define LCHUNK 32     // SEQLEN / NCHUNK

typedef __hip_bfloat16 bf16;
typedef __attribute__((ext_vector_type(8))) short short8;
typedef __attribute__((ext_vector_type(4))) float f32x4;

__device__ __forceinline__ unsigned short f2bf_bits(float f) {
    bf16 h = __float2bfloat16(f);
    return *(unsigned short*)&h;
}

__device__ __forceinline__ float softplus_f(float x) {
    return fmaxf(x, 0.f) + __logf(1.f + __expf(-fabsf(x)));
}

// async global->LDS 16B per lane; LDS dest must be wave-uniform base + lane*16.
__device__ __forceinline__ void load16_lds(void* lds, const void* g) {
    __builtin_amdgcn_global_load_lds(
        (const __attribute__((address_space(1))) unsigned int*)g,
        (__attribute__((address_space(3))) unsigned int*)lds, 16, 0, 0);
}

// ---------------- fused prep: weight transposes + x convert + A precompute ----
__device__ __forceinline__ void transpose_tile(const float* __restrict__ B,
                                               bf16* __restrict__ Bt,
                                               int K, int N, int nt, int kt,
                                               float (*t)[33], int tid)
{
    const int tx = tid & 31, ty = tid >> 5;
    const int n0 = nt * 32, k0 = kt * 32;
    #pragma unroll
    for (int r = 0; r < 4; ++r) {
        int n = n0 + tx;
        t[ty + r * 8][tx] = (n < N) ? B[(size_t)(k0 + ty + r * 8) * N + n] : 0.f;
    }
    __syncthreads();
    #pragma unroll
    for (int r = 0; r < 4; ++r)
        Bt[(size_t)(n0 + ty + r * 8) * K + k0 + tx] = __float2bfloat16(t[tx][ty + r * 8]);
}

__global__ __launch_bounds__(256)
void prep_kernel(const float* __restrict__ x, bf16* __restrict__ x_bf,
                 const float* __restrict__ W_in, bf16* __restrict__ Win_t,
                 const float* __restrict__ W_xproj, bf16* __restrict__ Wxp_t,
                 const float* __restrict__ W_dt, bf16* __restrict__ Wdt_t,
                 const float* __restrict__ W_out, bf16* __restrict__ Wout_t,
                 const float* __restrict__ A_log, float* __restrict__ Aneg)
{
    __shared__ float t[32][33];
    const int tid = threadIdx.x;
    int blk = blockIdx.x;
    if (blk < 4096) {            // W_in: K=1024, Npad=4096 -> 128 x 32 tiles
        transpose_tile(W_in, Win_t, D_MODEL, 2 * D_INNER, blk & 127, blk >> 7, t, tid);
        return;
    }
    blk -= 4096;
    if (blk < 512) {             // W_xproj: K=2048, Npad=256 -> 8 x 64 tiles
        transpose_tile(W_xproj, Wxp_t, D_INNER, XCOLS, blk & 7, blk >> 3, t, tid);
        return;
    }
    blk -= 512;
    if (blk < 256) {             // W_dt: K=128, N=2048 -> 64 x 4 tiles
        transpose_tile(W_dt, Wdt_t, DT_RANK, D_INNER, blk & 63, blk >> 6, t, tid);
        return;
    }
    blk -= 256;
    if (blk < 2048) {            // W_out: K=2048, N=1024 -> 32 x 64 tiles
        transpose_tile(W_out, Wout_t, D_INNER, D_MODEL, blk & 31, blk >> 5, t, tid);
        return;
    }
    blk -= 2048;
    if (blk < 2048) {            // x -> bf16, float4
        int i = blk * 256 + tid;
        float4 v = ((const float4*)x)[i];
        ushort4 p;
        p.x = f2bf_bits(v.x); p.y = f2bf_bits(v.y);
        p.z = f2bf_bits(v.z); p.w = f2bf_bits(v.w);
        ((ushort4*)x_bf)[i] = p;
        return;
    }
    blk -= 2048;
    {                            // Aneg = -exp(A_log)
        int i = blk * 256 + tid;
        Aneg[i] = -__expf(A_log[i]);
    }
}

// ---------------- MFMA GEMM (tile 128xBN, BK=32, split-K capable) ------------
// C_z[M,ldc] = A[M,kchunk] @ Bt[Npad,kchunk]^T, chunk z = blockIdx.z.
// 256 threads (4 waves). BN=128: wave=64x64 (4x4 mfma). BN=64: wave=64x32 (4x2).
// EPI=0: fp32 store to C. EPI=1: bf16 softplus(acc+bias[col]) to Cb.
// EPI=2: split xz: col<2048 -> fp32 to C (ldc 2048); col>=2048 -> bf16 to Cb.
template<int BN, int EPI>
__global__ __launch_bounds__(256)
void gemm_mfma(const bf16* __restrict__ A, const bf16* __restrict__ Bt,
               float* __restrict__ C, bf16* __restrict__ Cb,
               const float* __restrict__ bias,
               int M, int N, int K, int ldc, int kchunk)
{
    constexpr int WN = (BN == 128) ? 64 : 32;
    constexpr int NJ = WN / 16;
    __shared__ short As[128 * 32];
    __shared__ short Bs[BN * 32];
    const int tid = threadIdx.x;
    const int lane = tid & 63, wave = tid >> 6;
    const int wm = (wave >> 1) * 64, wn = (wave & 1) * WN;
    const int row0 = blockIdx.y * 128, col0 = blockIdx.x * BN;
    const int r_m = lane & 15, r_q = lane >> 4;
    const int kstart = blockIdx.z * kchunk;
    float* Cz = C + (size_t)blockIdx.z * M * ldc;

    // staging: thread t -> LDS byte 16*tid (wave-uniform base + lane*16)
    const int srow = tid >> 2, schk = (tid & 3) * 8;
    const bf16* Ag0 = A  + (size_t)(row0 + srow)      * K + kstart + schk;
    const bf16* Ag1 = A  + (size_t)(row0 + srow + 64) * K + kstart + schk;
    const bf16* Bg0 = Bt + (size_t)(col0 + srow)      * K + kstart + schk;
    const bf16* Bg1 = Bt + (size_t)(col0 + srow + 64) * K + kstart + schk; // BN=128 only
    short* AsW0 = &As[8 * tid];
    short* AsW1 = &As[8 * tid + 2048];
    short* BsW0 = &Bs[8 * tid];
    short* BsW1 = &Bs[8 * tid + 2048];

    f32x4 acc[4][NJ];
    #pragma unroll
    for (int i = 0; i < 4; ++i)
        #pragma unroll
        for (int j = 0; j < NJ; ++j)
            #pragma unroll
            for (int r = 0; r < 4; ++r) acc[i][j][r] = 0.f;

    for (int k0 = 0; k0 < kchunk; k0 += 32) {
        __syncthreads();                 // prev-iter LDS reads done
        load16_lds(AsW0, Ag0 + k0);
        load16_lds(AsW1, Ag1 + k0);
        load16_lds(BsW0, Bg0 + k0);
        if (BN == 128) load16_lds(BsW1, Bg1 + k0);
        __syncthreads();                 // drains vmcnt -> staging visible
        short8 af[4], bfr[NJ];
        #pragma unroll
        for (int i = 0; i < 4; ++i)
            af[i] = *(const short8*)&As[(wm + i * 16 + r_m) * 32 + r_q * 8];
        #pragma unroll
        for (int j = 0; j < NJ; ++j)
            bfr[j] = *(const short8*)&Bs[(wn + j * 16 + r_m) * 32 + r_q * 8];
        #pragma unroll
        for (int i = 0; i < 4; ++i)
            #pragma unroll
            for (int j = 0; j < NJ; ++j)
                acc[i][j] = __builtin_amdgcn_mfma_f32_16x16x32_bf16(
                    af[i], bfr[j], acc[i][j], 0, 0, 0);
    }

    #pragma unroll
    for (int i = 0; i < 4; ++i) {
        #pragma unroll
        for (int j = 0; j < NJ; ++j) {
            int row = row0 + wm + i * 16 + r_q * 4;
            int col = col0 + wn + j * 16 + r_m;
            if (col < N) {
                if (EPI == 1) {
                    float bv = bias[col];
                    #pragma unroll
                    for (int r = 0; r < 4; ++r)
                        Cb[(size_t)(row + r) * ldc + col] =
                            __float2bfloat16(softplus_f(acc[i][j][r] + bv));
                } else if (EPI == 2) {
                    if (col < D_INNER) {
                        #pragma unroll
                        for (int r = 0; r < 4; ++r)
                            Cz[(size_t)(row + r) * D_INNER + col] = acc[i][j][r];
                    } else {
                        #pragma unroll
                        for (int r = 0; r < 4; ++r)
                            Cb[(size_t)(row + r) * D_INNER + (col - D_INNER)] =
                                __float2bfloat16(acc[i][j][r]);
                    }
                } else {
                    #pragma unroll
                    for (int r = 0; r < 4; ++r)
                        Cz[(size_t)(row + r) * ldc + col] = acc[i][j][r];
                }
            }
        }
    }
}

// reduce 8 split-K partials (ldc=256) -> x_dbl fp32 (160 cols) + dt_low bf16
__global__ __launch_bounds__(256)
void reduce_xdbl(const float* __restrict__ Cpart, float* __restrict__ x_dbl,
                 bf16* __restrict__ dtA_bf)
{
    int i = blockIdx.x * 256 + threadIdx.x;          // 2048*160
    if (i >= 2048 * XCOLS) return;
    int r = i / XCOLS, c = i - r * XCOLS;
    float s = 0.f;
    #pragma unroll
    for (int z = 0; z < 8; ++z)
        s += Cpart[(size_t)z * 2048 * 256 + (size_t)r * 256 + c];
    x_dbl[i] = s;
    if (c < DT_RANK) dtA_bf[(size_t)r * DT_RANK + c] = __float2bfloat16(s);
}

// reduce 2 split-K partials -> out fp32, float4
__global__ __launch_bounds__(256)
void reduce_out(const float* __restrict__ Cpart, float* __restrict__ out)
{
    int i = blockIdx.x * 256 + threadIdx.x;          // (2048*1024)/4
    const float4* p0 = (const float4*)Cpart;
    const float4* p1 = p0 + (size_t)2048 * 1024 / 4;
    float4 a = p0[i], b = p1[i];
    float4 r; r.x = a.x + b.x; r.y = a.y + b.y; r.z = a.z + b.z; r.w = a.w + b.w;
    ((float4*)out)[i] = r;
}

// ---------------- conv + silu (float4 over d), bf16 output only --------------
// xz32: (B*L, 2048) fp32 (x_in half only)
__global__ __launch_bounds__(256)
void conv_silu_kernel(const float* __restrict__ xz32,
                      const float* __restrict__ conv_k,
                      const float* __restrict__ conv_b,
                      bf16* __restrict__ u_bf)
{
    int idx4 = blockIdx.x * 256 + threadIdx.x;       // B*L*Di/4 = 1048576
    int d4 = idx4 & (D_INNER / 4 - 1);
    int t = (idx4 >> 9) & (SEQLEN - 1);
    int b = idx4 >> 19;
    float4 acc = ((const float4*)conv_b)[d4];
    #pragma unroll
    for (int k = 0; k < D_CONV; ++k) {
        int tt = t + k - (D_CONV - 1);
        if (tt >= 0) {
            float4 xv = ((const float4*)xz32)[(size_t)(b * SEQLEN + tt) * (D_INNER / 4) + d4];
            float4 kv = ((const float4*)conv_k)[k * (D_INNER / 4) + d4];
            acc.x = fmaf(xv.x, kv.x, acc.x);
            acc.y = fmaf(xv.y, kv.y, acc.y);
            acc.z = fmaf(xv.z, kv.z, acc.z);
            acc.w = fmaf(xv.w, kv.w, acc.w);
        }
    }
    ushort4 pk;
    pk.x = f2bf_bits(acc.x / (1.f + __expf(-acc.x)));
    pk.y = f2bf_bits(acc.y / (1.f + __expf(-acc.y)));
    pk.z = f2bf_bits(acc.z / (1.f + __expf(-acc.z)));
    pk.w = f2bf_bits(acc.w / (1.f + __expf(-acc.w)));
    ((ushort4*)u_bf)[idx4] = pk;
}

// ---------------- chunked scan (NCHUNK=32, LCHUNK=32) ----------------
__global__ __launch_bounds__(256)
void scan_phase1(const bf16* __restrict__ dt_sb,
                 const float* __restrict__ Aneg,
                 const bf16* __restrict__ u_bf,
                 const float* __restrict__ x_dbl,
                 float* __restrict__ Pst, float* __restrict__ Sst)
{
    __shared__ float Bsm[LCHUNK][16];
    const int d = blockIdx.x * 256 + threadIdx.x;
    const int c = blockIdx.y, b = blockIdx.z;
    const int t0 = c * LCHUNK;
    for (int i = threadIdx.x; i < LCHUNK * 16; i += 256) {
        int tt = i >> 4, n = i & 15;
        Bsm[tt][n] = x_dbl[(size_t)(b * SEQLEN + t0 + tt) * XCOLS + DT_RANK + n];
    }
    float A_row[D_STATE];
    const float4* a4 = (const float4*)(Aneg + d * D_STATE);
    #pragma unroll
    for (int q = 0; q < 4; ++q) {
        float4 v = a4[q];
        A_row[q*4+0] = v.x; A_row[q*4+1] = v.y; A_row[q*4+2] = v.z; A_row[q*4+3] = v.w;
    }
    __syncthreads();
    float P[D_STATE], S[D_STATE];
    #pragma unroll
    for (int n = 0; n < D_STATE; ++n) { P[n] = 1.f; S[n] = 0.f; }
    const bf16* dpp = dt_sb + (size_t)(b * SEQLEN + t0) * D_INNER + d;
    const bf16* upp = u_bf + (size_t)(b * SEQLEN + t0) * D_INNER + d;
    #pragma unroll 8
    for (int t = 0; t < LCHUNK; ++t) {
        float dtv = __bfloat162float(dpp[(size_t)t * D_INNER]);
        float du = dtv * __bfloat162float(upp[(size_t)t * D_INNER]);
        const float4* b4 = (const float4*)&Bsm[t][0];
        #pragma unroll
        for (int q = 0; q < 4; ++q) {
            float4 v = b4[q];
            float Bn[4] = {v.x, v.y, v.z, v.w};
            #pragma unroll
            for (int e = 0; e < 4; ++e) {
                int n = q * 4 + e;
                float a = __expf(dtv * A_row[n]);
                P[n] *= a;
                S[n] = fmaf(a, S[n], du * Bn[e]);
            }
        }
    }
    const size_t base = ((size_t)(b * NCHUNK + c) * D_STATE) * D_INNER + d;
    #pragma unroll
    for (int n = 0; n < D_STATE; ++n) {
        Pst[base + (size_t)n * D_INNER] = P[n];
        Sst[base + (size_t)n * D_INNER] = S[n];
    }
}

// Phase 2: combine chunk transforms; write h_in per chunk IN-PLACE over Sst.
__global__ __launch_bounds__(256)
void scan_phase2(const float* __restrict__ Pst, float* __restrict__ Sst)
{
    const int d = blockIdx.x * 256 + threadIdx.x;
    const int n = blockIdx.y;
    const int b = blockIdx.z;
    float h = 0.f;
    for (int c = 0; c < NCHUNK; ++c) {
        const size_t idx = ((size_t)(b * NCHUNK + c) * D_STATE + n) * D_INNER + d;
        float Pv = Pst[idx], Sv = Sst[idx];
        Sst[idx] = h;                       // h_in for chunk c
        h = fmaf(Pv, h, Sv);
    }
}

__global__ __launch_bounds__(256)
void scan_phase3(const bf16* __restrict__ dt_sb,
                 const float* __restrict__ Aneg,
                 const bf16* __restrict__ u_bf,
                 const float* __restrict__ x_dbl,
                 const float* __restrict__ Dvec,
                 const bf16* __restrict__ z_bf,
                 const float* __restrict__ hin,   // == Sst after phase2
                 bf16* __restrict__ g_bf)
{
    __shared__ float BCs[LCHUNK][32];
    const int d = blockIdx.x * 256 + threadIdx.x;
    const int c = blockIdx.y, b = blockIdx.z;
    const int t0 = c * LCHUNK;
    for (int i = threadIdx.x; i < LCHUNK * 32; i += 256) {
        int tt = i >> 5, col = i & 31;
        BCs[tt][col] = x_dbl[(size_t)(b * SEQLEN + t0 + tt) * XCOLS + DT_RANK + col];
    }
    float A_row[D_STATE];
    const float4* a4 = (const float4*)(Aneg + d * D_STATE);
    #pragma unroll
    for (int q = 0; q < 4; ++q) {
        float4 v = a4[q];
        A_row[q*4+0] = v.x; A_row[q*4+1] = v.y; A_row[q*4+2] = v.z; A_row[q*4+3] = v.w;
    }
    const float Dd = Dvec[d];
    __syncthreads();
    float h[D_STATE];
    const size_t base = ((size_t)(b * NCHUNK + c) * D_STATE) * D_INNER + d;
    #pragma unroll
    for (int n = 0; n < D_STATE; ++n) h[n] = hin[base + (size_t)n * D_INNER];
    const bf16* dpp = dt_sb + (size_t)(b * SEQLEN + t0) * D_INNER + d;
    const bf16* upp = u_bf + (size_t)(b * SEQLEN + t0) * D_INNER + d;
    const bf16* zpp = z_bf + (size_t)(b * SEQLEN + t0) * D_INNER + d;
    bf16* gpp = g_bf + (size_t)(b * SEQLEN + t0) * D_INNER + d;
    #pragma unroll 8
    for (int t = 0; t < LCHUNK; ++t) {
        float dtv = __bfloat162float(dpp[(size_t)t * D_INNER]);
        float uv = __bfloat162float(upp[(size_t)t * D_INNER]);
        float zv = __bfloat162float(zpp[(size_t)t * D_INNER]);
        float du = dtv * uv;
        float y = 0.f;
        const float4* bc4 = (const float4*)&BCs[t][0];
        #pragma unroll
        for (int q = 0; q < 4; ++q) {
            float4 v = bc4[q];
            float4 w = bc4[q + 4];
            float Bn[4] = {v.x, v.y, v.z, v.w};
            float Cn[4] = {w.x, w.y, w.z, w.w};
            #pragma unroll
            for (int e = 0; e < 4; ++e) {
                int n = q * 4 + e;
                float a = __expf(dtv * A_row[n]);
                h[n] = fmaf(a, h[n], du * Bn[e]);
                y = fmaf(h[n], Cn[e], y);
            }
        }
        float gy = y + uv * Dd;
        float sz = zv / (1.f + __expf(-zv));
        gpp[(size_t)t * D_INNER] = __float2bfloat16(gy * sz);
    }
}

extern "C" void kernel_launch(void* const* d_in, const int* in_sizes, int n_in,
                              void* d_out, int out_size, void* d_ws, size_t ws_size,
                              hipStream_t stream)
{
    const float* x      = (const float*)d_in[0];
    const float* W_in   = (const float*)d_in[1];
    const float* conv_k = (const float*)d_in[2];
    const float* conv_b = (const float*)d_in[3];
    const float* W_xproj= (const float*)d_in[4];
    const float* W_dt   = (const float*)d_in[5];
    const float* b_dt   = (const float*)d_in[6];
    const float* A_log  = (const float*)d_in[7];
    const float* Dvec   = (const float*)d_in[8];
    const float* W_out  = (const float*)d_in[9];
    float* out = (float*)d_out;

    const int BL = BATCH * SEQLEN;                    // 2048
    const size_t PS_ELEMS = (size_t)BATCH * NCHUNK * D_STATE * D_INNER; // 2,097,152

    // fp32 region
    float* ws     = (float*)d_ws;
    float* xz32   = ws;                                 // 4,194,304 (x_in half, fp32)
    float* x_dbl  = xz32   + (size_t)BL * D_INNER;      //   327,680
    float* Pst    = x_dbl  + (size_t)BL * XCOLS;        // 2,097,152
    float* Sst    = Pst    + PS_ELEMS;                  // 2,097,152
    float* extraC = Sst    + PS_ELEMS;                  // 4,194,304 extra for Cpart
    float* Aneg   = extraC + (size_t)4194304;           // 32,768
    float* Cpart3 = Pst;     // 8 x 2048 x 256 = 4,194,304 (Pst/Sst dead then)
    float* Cpart6 = Pst;     // 2 x 2048 x 1024 = 4,194,304 (dead after phase3)
    bf16*  x_bf   = (bf16*)extraC;  // 2048x1024 bf16, dead after G1
    // bf16 region
    bf16* Win_t  = (bf16*)(Aneg + 32768);               // 4096 x 1024
    bf16* u_bf   = Win_t + (size_t)4096 * 1024;         // 2048 x 2048
    bf16* Wxp_t  = u_bf  + (size_t)BL * D_INNER;        // 256  x 2048 (padded)
    bf16* dtA_bf = Wxp_t + (size_t)256 * 2048;          // 2048 x 128
    bf16* Wdt_t  = dtA_bf+ (size_t)BL * DT_RANK;        // 2048 x 128
    bf16* g_bf   = Wdt_t + (size_t)2048 * 128;          // 2048 x 2048
    bf16* Wout_t = g_bf  + (size_t)BL * D_INNER;        // 1024 x 2048
    bf16* dt_sb  = Wout_t+ (size_t)1024 * 2048;         // 2048 x 2048
    bf16* z_bf   = dt_sb + (size_t)BL * D_INNER;        // 2048 x 2048

    // 0) fused prep: 4 transposes + x convert + Aneg
    prep_kernel<<<4096 + 512 + 256 + 2048 + 2048 + 128, 256, 0, stream>>>(
        x, x_bf, W_in, Win_t, W_xproj, Wxp_t, W_dt, Wdt_t, W_out, Wout_t, A_log, Aneg);

    // 1) xz = x @ W_in; x_in half -> fp32 xz32, z half -> bf16 z_bf
    gemm_mfma<128, 2><<<dim3(32, 16, 1), 256, 0, stream>>>(
        x_bf, Win_t, xz32, z_bf, nullptr, BL, 2 * D_INNER, D_MODEL, D_INNER, D_MODEL);

    // 2) u_bf = bf16(silu(causal_conv(xz32) + b))
    conv_silu_kernel<<<(BL * D_INNER / 4) / 256, 256, 0, stream>>>(xz32, conv_k, conv_b, u_bf);

    // 3) x_dbl = u @ W_xproj  split-K 8, BN=64 -> 512 blocks
    gemm_mfma<64, 0><<<dim3(4, 16, 8), 256, 0, stream>>>(
        u_bf, Wxp_t, Cpart3, nullptr, nullptr, BL, 256, D_INNER, 256, 256);
    reduce_xdbl<<<(BL * XCOLS + 255) / 256, 256, 0, stream>>>(Cpart3, x_dbl, dtA_bf);

    // 4) dt_sb = bf16(softplus(dt_low @ W_dt + b_dt)), BN=64 -> 512 blocks
    gemm_mfma<64, 1><<<dim3(32, 16, 1), 256, 0, stream>>>(
        dtA_bf, Wdt_t, nullptr, dt_sb, b_dt, BL, D_INNER, DT_RANK, D_INNER, DT_RANK);

    // 5) chunked selective scan -> g_bf = bf16((y + u*D) * silu(z))
    scan_phase1<<<dim3(D_INNER / 256, NCHUNK, BATCH), 256, 0, stream>>>(
        dt_sb, Aneg, u_bf, x_dbl, Pst, Sst);
    scan_phase2<<<dim3(D_INNER / 256, D_STATE, BATCH), 256, 0, stream>>>(Pst, Sst);
    scan_phase3<<<dim3(D_INNER / 256, NCHUNK, BATCH), 256, 0, stream>>>(
        dt_sb, Aneg, u_bf, x_dbl, Dvec, z_bf, Sst, g_bf);

    // 6) out = g @ W_out  split-K 2, BN=64 -> 512 blocks
    gemm_mfma<64, 0><<<dim3(16, 16, 2), 256, 0, stream>>>(
        g_bf, Wout_t, Cpart6, nullptr, nullptr, BL, D_MODEL, D_INNER, D_MODEL, D_MODEL);
    reduce_out<<<(BL * D_MODEL / 4) / 256, 256, 0, stream>>>(Cpart6, out);
}

// Round 9
// 237.059 us; speedup vs baseline: 1.0793x; 1.0793x over previous
//
#include <hip/hip_runtime.h>
#include <hip/hip_bf16.h>

#define D_MODEL 1024
#define D_STATE 16
#define D_CONV 4
#define D_INNER 2048
#define DT_RANK 128
#define BATCH 2
#define SEQLEN 1024
#define XCOLS 160     // DT_RANK + 2*D_STATE
#define NCHUNK 64
#define LCHUNK 16     // SEQLEN / NCHUNK

typedef __hip_bfloat16 bf16;
typedef __attribute__((ext_vector_type(8))) short short8;
typedef __attribute__((ext_vector_type(4))) float f32x4;

__device__ __forceinline__ unsigned short f2bf_bits(float f) {
    bf16 h = __float2bfloat16(f);
    return *(unsigned short*)&h;
}

__device__ __forceinline__ float softplus_f(float x) {
    return fmaxf(x, 0.f) + __logf(1.f + __expf(-fabsf(x)));
}

// async global->LDS 16B per lane; LDS dest must be wave-uniform base + lane*16.
__device__ __forceinline__ void load16_lds(void* lds, const void* g) {
    __builtin_amdgcn_global_load_lds(
        (const __attribute__((address_space(1))) unsigned int*)g,
        (__attribute__((address_space(3))) unsigned int*)lds, 16, 0, 0);
}

// ---------------- fused prep: weight transposes + x convert + A precompute ----
__device__ __forceinline__ void transpose_tile(const float* __restrict__ B,
                                               bf16* __restrict__ Bt,
                                               int K, int N, int nt, int kt,
                                               float (*t)[33], int tid)
{
    const int tx = tid & 31, ty = tid >> 5;
    const int n0 = nt * 32, k0 = kt * 32;
    #pragma unroll
    for (int r = 0; r < 4; ++r) {
        int n = n0 + tx;
        t[ty + r * 8][tx] = (n < N) ? B[(size_t)(k0 + ty + r * 8) * N + n] : 0.f;
    }
    __syncthreads();
    #pragma unroll
    for (int r = 0; r < 4; ++r)
        Bt[(size_t)(n0 + ty + r * 8) * K + k0 + tx] = __float2bfloat16(t[tx][ty + r * 8]);
}

__global__ __launch_bounds__(256)
void prep_kernel(const float* __restrict__ x, bf16* __restrict__ x_bf,
                 const float* __restrict__ W_in, bf16* __restrict__ Win_t,
                 const float* __restrict__ W_xproj, bf16* __restrict__ Wxp_t,
                 const float* __restrict__ W_dt, bf16* __restrict__ Wdt_t,
                 const float* __restrict__ W_out, bf16* __restrict__ Wout_t,
                 const float* __restrict__ A_log, float* __restrict__ Aneg)
{
    __shared__ float t[32][33];
    const int tid = threadIdx.x;
    int blk = blockIdx.x;
    if (blk < 4096) {            // W_in: K=1024, Npad=4096 -> 128 x 32 tiles
        transpose_tile(W_in, Win_t, D_MODEL, 2 * D_INNER, blk & 127, blk >> 7, t, tid);
        return;
    }
    blk -= 4096;
    if (blk < 512) {             // W_xproj: K=2048, Npad=256 -> 8 x 64 tiles
        transpose_tile(W_xproj, Wxp_t, D_INNER, XCOLS, blk & 7, blk >> 3, t, tid);
        return;
    }
    blk -= 512;
    if (blk < 256) {             // W_dt: K=128, N=2048 -> 64 x 4 tiles
        transpose_tile(W_dt, Wdt_t, DT_RANK, D_INNER, blk & 63, blk >> 6, t, tid);
        return;
    }
    blk -= 256;
    if (blk < 2048) {            // W_out: K=2048, N=1024 -> 32 x 64 tiles
        transpose_tile(W_out, Wout_t, D_INNER, D_MODEL, blk & 31, blk >> 5, t, tid);
        return;
    }
    blk -= 2048;
    if (blk < 2048) {            // x -> bf16, float4
        int i = blk * 256 + tid;
        float4 v = ((const float4*)x)[i];
        ushort4 p;
        p.x = f2bf_bits(v.x); p.y = f2bf_bits(v.y);
        p.z = f2bf_bits(v.z); p.w = f2bf_bits(v.w);
        ((ushort4*)x_bf)[i] = p;
        return;
    }
    blk -= 2048;
    {                            // Aneg = -exp(A_log)
        int i = blk * 256 + tid;
        Aneg[i] = -__expf(A_log[i]);
    }
}

// ---------------- MFMA GEMM (tile 128xBN, BK=32, split-K capable) ------------
// C_z[M,ldc] = A[M,kchunk] @ Bt[Npad,kchunk]^T, chunk z = blockIdx.z.
// 256 threads (4 waves). BN=128: wave=64x64 (4x4 mfma). BN=64: wave=64x32 (4x2).
// EPI=0: fp32 store to C. EPI=1: bf16 softplus(acc+bias[col]) to Cb.
// EPI=2: split xz: col<2048 -> fp32 to C (ld 2048); col>=2048 -> bf16 to Cb.
template<int BN, int EPI>
__global__ __launch_bounds__(256)
void gemm_mfma(const bf16* __restrict__ A, const bf16* __restrict__ Bt,
               float* __restrict__ C, bf16* __restrict__ Cb,
               const float* __restrict__ bias,
               int M, int N, int K, int ldc, int kchunk)
{
    constexpr int WN = (BN == 128) ? 64 : 32;
    constexpr int NJ = WN / 16;
    __shared__ short As[128 * 32];
    __shared__ short Bs[BN * 32];
    const int tid = threadIdx.x;
    const int lane = tid & 63, wave = tid >> 6;
    const int wm = (wave >> 1) * 64, wn = (wave & 1) * WN;
    const int row0 = blockIdx.y * 128, col0 = blockIdx.x * BN;
    const int r_m = lane & 15, r_q = lane >> 4;
    const int kstart = blockIdx.z * kchunk;
    float* Cz = C + (size_t)blockIdx.z * M * ldc;

    // staging: thread t -> LDS byte 16*tid (wave-uniform base + lane*16)
    const int srow = tid >> 2, schk = (tid & 3) * 8;
    const bf16* Ag0 = A  + (size_t)(row0 + srow)      * K + kstart + schk;
    const bf16* Ag1 = A  + (size_t)(row0 + srow + 64) * K + kstart + schk;
    const bf16* Bg0 = Bt + (size_t)(col0 + srow)      * K + kstart + schk;
    const bf16* Bg1 = Bt + (size_t)(col0 + srow + 64) * K + kstart + schk; // BN=128 only
    short* AsW0 = &As[8 * tid];
    short* AsW1 = &As[8 * tid + 2048];
    short* BsW0 = &Bs[8 * tid];
    short* BsW1 = &Bs[8 * tid + 2048];

    f32x4 acc[4][NJ];
    #pragma unroll
    for (int i = 0; i < 4; ++i)
        #pragma unroll
        for (int j = 0; j < NJ; ++j)
            #pragma unroll
            for (int r = 0; r < 4; ++r) acc[i][j][r] = 0.f;

    for (int k0 = 0; k0 < kchunk; k0 += 32) {
        __syncthreads();                 // prev-iter LDS reads done
        load16_lds(AsW0, Ag0 + k0);
        load16_lds(AsW1, Ag1 + k0);
        load16_lds(BsW0, Bg0 + k0);
        if (BN == 128) load16_lds(BsW1, Bg1 + k0);
        __syncthreads();                 // drains vmcnt -> staging visible
        short8 af[4], bfr[NJ];
        #pragma unroll
        for (int i = 0; i < 4; ++i)
            af[i] = *(const short8*)&As[(wm + i * 16 + r_m) * 32 + r_q * 8];
        #pragma unroll
        for (int j = 0; j < NJ; ++j)
            bfr[j] = *(const short8*)&Bs[(wn + j * 16 + r_m) * 32 + r_q * 8];
        #pragma unroll
        for (int i = 0; i < 4; ++i)
            #pragma unroll
            for (int j = 0; j < NJ; ++j)
                acc[i][j] = __builtin_amdgcn_mfma_f32_16x16x32_bf16(
                    af[i], bfr[j], acc[i][j], 0, 0, 0);
    }

    #pragma unroll
    for (int i = 0; i < 4; ++i) {
        #pragma unroll
        for (int j = 0; j < NJ; ++j) {
            int row = row0 + wm + i * 16 + r_q * 4;
            int col = col0 + wn + j * 16 + r_m;
            if (col < N) {
                if (EPI == 1) {
                    float bv = bias[col];
                    #pragma unroll
                    for (int r = 0; r < 4; ++r)
                        Cb[(size_t)(row + r) * ldc + col] =
                            __float2bfloat16(softplus_f(acc[i][j][r] + bv));
                } else if (EPI == 2) {
                    if (col < D_INNER) {
                        #pragma unroll
                        for (int r = 0; r < 4; ++r)
                            Cz[(size_t)(row + r) * D_INNER + col] = acc[i][j][r];
                    } else {
                        #pragma unroll
                        for (int r = 0; r < 4; ++r)
                            Cb[(size_t)(row + r) * D_INNER + (col - D_INNER)] =
                                __float2bfloat16(acc[i][j][r]);
                    }
                } else {
                    #pragma unroll
                    for (int r = 0; r < 4; ++r)
                        Cz[(size_t)(row + r) * ldc + col] = acc[i][j][r];
                }
            }
        }
    }
}

// reduce 8 split-K partials (ldc=256) -> x_dbl fp32 (160 cols) + dt_low bf16
__global__ __launch_bounds__(256)
void reduce_xdbl(const float* __restrict__ Cpart, float* __restrict__ x_dbl,
                 bf16* __restrict__ dtA_bf)
{
    int i = blockIdx.x * 256 + threadIdx.x;          // 2048*160
    if (i >= 2048 * XCOLS) return;
    int r = i / XCOLS, c = i - r * XCOLS;
    float s = 0.f;
    #pragma unroll
    for (int z = 0; z < 8; ++z)
        s += Cpart[(size_t)z * 2048 * 256 + (size_t)r * 256 + c];
    x_dbl[i] = s;
    if (c < DT_RANK) dtA_bf[(size_t)r * DT_RANK + c] = __float2bfloat16(s);
}

// reduce 2 split-K partials -> out fp32, float4
__global__ __launch_bounds__(256)
void reduce_out(const float* __restrict__ Cpart, float* __restrict__ out)
{
    int i = blockIdx.x * 256 + threadIdx.x;          // (2048*1024)/4
    const float4* p0 = (const float4*)Cpart;
    const float4* p1 = p0 + (size_t)2048 * 1024 / 4;
    float4 a = p0[i], b = p1[i];
    float4 r; r.x = a.x + b.x; r.y = a.y + b.y; r.z = a.z + b.z; r.w = a.w + b.w;
    ((float4*)out)[i] = r;
}

// ---------------- conv + silu (float4 over d), bf16 output only --------------
__global__ __launch_bounds__(256)
void conv_silu_kernel(const float* __restrict__ xz32,
                      const float* __restrict__ conv_k,
                      const float* __restrict__ conv_b,
                      bf16* __restrict__ u_bf)
{
    int idx4 = blockIdx.x * 256 + threadIdx.x;       // B*L*Di/4 = 1048576
    int d4 = idx4 & (D_INNER / 4 - 1);
    int t = (idx4 >> 9) & (SEQLEN - 1);
    int b = idx4 >> 19;
    float4 acc = ((const float4*)conv_b)[d4];
    #pragma unroll
    for (int k = 0; k < D_CONV; ++k) {
        int tt = t + k - (D_CONV - 1);
        if (tt >= 0) {
            float4 xv = ((const float4*)xz32)[(size_t)(b * SEQLEN + tt) * (D_INNER / 4) + d4];
            float4 kv = ((const float4*)conv_k)[k * (D_INNER / 4) + d4];
            acc.x = fmaf(xv.x, kv.x, acc.x);
            acc.y = fmaf(xv.y, kv.y, acc.y);
            acc.z = fmaf(xv.z, kv.z, acc.z);
            acc.w = fmaf(xv.w, kv.w, acc.w);
        }
    }
    ushort4 pk;
    pk.x = f2bf_bits(acc.x / (1.f + __expf(-acc.x)));
    pk.y = f2bf_bits(acc.y / (1.f + __expf(-acc.y)));
    pk.z = f2bf_bits(acc.z / (1.f + __expf(-acc.z)));
    pk.w = f2bf_bits(acc.w / (1.f + __expf(-acc.w)));
    ((ushort4*)u_bf)[idx4] = pk;
}

// ---------------- chunked scan (NCHUNK=64, LCHUNK=16) ----------------
// Phases 1/3: thread = (d, half); each owns 8 of 16 states. 2048 blocks ->
// 8192 waves = 32 waves/CU (occupancy cap), vs 16 with one-thread-per-d.
__global__ __launch_bounds__(256)
void scan_phase1(const bf16* __restrict__ dt_sb,
                 const float* __restrict__ Aneg,
                 const bf16* __restrict__ u_bf,
                 const float* __restrict__ x_dbl,
                 float* __restrict__ Pst, float* __restrict__ Sst)
{
    __shared__ float Bsm[LCHUNK][16];
    const int half = threadIdx.x & 1;         // 0/1: states [0,8) or [8,16)
    const int d = blockIdx.x * 128 + (threadIdx.x >> 1);
    const int c = blockIdx.y, b = blockIdx.z;
    const int t0 = c * LCHUNK;
    {   // stage B rows: LCHUNK*16 = 256 elems, one per thread
        int tt = threadIdx.x >> 4, n = threadIdx.x & 15;
        Bsm[tt][n] = x_dbl[(size_t)(b * SEQLEN + t0 + tt) * XCOLS + DT_RANK + n];
    }
    float A_row[8];
    {
        const float4* a4 = (const float4*)(Aneg + d * D_STATE + half * 8);
        float4 v0 = a4[0], v1 = a4[1];
        A_row[0]=v0.x; A_row[1]=v0.y; A_row[2]=v0.z; A_row[3]=v0.w;
        A_row[4]=v1.x; A_row[5]=v1.y; A_row[6]=v1.z; A_row[7]=v1.w;
    }
    __syncthreads();
    float P[8], S[8];
    #pragma unroll
    for (int e = 0; e < 8; ++e) { P[e] = 1.f; S[e] = 0.f; }
    const bf16* dpp = dt_sb + (size_t)(b * SEQLEN + t0) * D_INNER + d;
    const bf16* upp = u_bf + (size_t)(b * SEQLEN + t0) * D_INNER + d;
    #pragma unroll
    for (int t = 0; t < LCHUNK; ++t) {
        float dtv = __bfloat162float(dpp[(size_t)t * D_INNER]);
        float du = dtv * __bfloat162float(upp[(size_t)t * D_INNER]);
        const float* brow = &Bsm[t][half * 8];
        #pragma unroll
        for (int e = 0; e < 8; ++e) {
            float a = __expf(dtv * A_row[e]);
            P[e] *= a;
            S[e] = fmaf(a, S[e], du * brow[e]);
        }
    }
    const size_t base = ((size_t)(b * NCHUNK + c) * D_STATE + half * 8) * D_INNER + d;
    #pragma unroll
    for (int e = 0; e < 8; ++e) {
        Pst[base + (size_t)e * D_INNER] = P[e];
        Sst[base + (size_t)e * D_INNER] = S[e];
    }
}

// Phase 2: combine chunk transforms; write h_in per chunk IN-PLACE over Sst.
__global__ __launch_bounds__(256)
void scan_phase2(const float* __restrict__ Pst, float* __restrict__ Sst)
{
    const int d = blockIdx.x * 256 + threadIdx.x;
    const int n = blockIdx.y;
    const int b = blockIdx.z;
    float h = 0.f;
    #pragma unroll 8
    for (int c = 0; c < NCHUNK; ++c) {
        const size_t idx = ((size_t)(b * NCHUNK + c) * D_STATE + n) * D_INNER + d;
        float Pv = Pst[idx], Sv = Sst[idx];
        Sst[idx] = h;                       // h_in for chunk c
        h = fmaf(Pv, h, Sv);
    }
}

__global__ __launch_bounds__(256)
void scan_phase3(const bf16* __restrict__ dt_sb,
                 const float* __restrict__ Aneg,
                 const bf16* __restrict__ u_bf,
                 const float* __restrict__ x_dbl,
                 const float* __restrict__ Dvec,
                 const bf16* __restrict__ z_bf,
                 const float* __restrict__ hin,   // == Sst after phase2
                 bf16* __restrict__ g_bf)
{
    __shared__ float BCs[LCHUNK][32];
    const int half = threadIdx.x & 1;
    const int d = blockIdx.x * 128 + (threadIdx.x >> 1);
    const int c = blockIdx.y, b = blockIdx.z;
    const int t0 = c * LCHUNK;
    {   // stage B and C rows: LCHUNK*32 = 512 elems, two per thread
        int i0 = threadIdx.x;
        int tt = i0 >> 5, col = i0 & 31;
        BCs[tt][col] = x_dbl[(size_t)(b * SEQLEN + t0 + tt) * XCOLS + DT_RANK + col];
        int i1 = i0 + 256;
        tt = i1 >> 5; col = i1 & 31;
        BCs[tt][col] = x_dbl[(size_t)(b * SEQLEN + t0 + tt) * XCOLS + DT_RANK + col];
    }
    float A_row[8];
    {
        const float4* a4 = (const float4*)(Aneg + d * D_STATE + half * 8);
        float4 v0 = a4[0], v1 = a4[1];
        A_row[0]=v0.x; A_row[1]=v0.y; A_row[2]=v0.z; A_row[3]=v0.w;
        A_row[4]=v1.x; A_row[5]=v1.y; A_row[6]=v1.z; A_row[7]=v1.w;
    }
    const float Dd = Dvec[d];
    __syncthreads();
    float h[8];
    const size_t base = ((size_t)(b * NCHUNK + c) * D_STATE + half * 8) * D_INNER + d;
    #pragma unroll
    for (int e = 0; e < 8; ++e) h[e] = hin[base + (size_t)e * D_INNER];
    const bf16* dpp = dt_sb + (size_t)(b * SEQLEN + t0) * D_INNER + d;
    const bf16* upp = u_bf + (size_t)(b * SEQLEN + t0) * D_INNER + d;
    const bf16* zpp = z_bf + (size_t)(b * SEQLEN + t0) * D_INNER + d;
    bf16* gpp = g_bf + (size_t)(b * SEQLEN + t0) * D_INNER + d;
    #pragma unroll
    for (int t = 0; t < LCHUNK; ++t) {
        float dtv = __bfloat162float(dpp[(size_t)t * D_INNER]);
        float uv = __bfloat162float(upp[(size_t)t * D_INNER]);
        float du = dtv * uv;
        float y = 0.f;
        const float* brow = &BCs[t][half * 8];
        const float* crow = &BCs[t][16 + half * 8];
        #pragma unroll
        for (int e = 0; e < 8; ++e) {
            float a = __expf(dtv * A_row[e]);
            h[e] = fmaf(a, h[e], du * brow[e]);
            y = fmaf(h[e], crow[e], y);
        }
        y += __shfl_xor(y, 1, 64);           // combine the two halves
        if (half == 0) {
            float zv = __bfloat162float(zpp[(size_t)t * D_INNER]);
            float gy = y + uv * Dd;
            float sz = zv / (1.f + __expf(-zv));
            gpp[(size_t)t * D_INNER] = __float2bfloat16(gy * sz);
        }
    }
}

extern "C" void kernel_launch(void* const* d_in, const int* in_sizes, int n_in,
                              void* d_out, int out_size, void* d_ws, size_t ws_size,
                              hipStream_t stream)
{
    const float* x      = (const float*)d_in[0];
    const float* W_in   = (const float*)d_in[1];
    const float* conv_k = (const float*)d_in[2];
    const float* conv_b = (const float*)d_in[3];
    const float* W_xproj= (const float*)d_in[4];
    const float* W_dt   = (const float*)d_in[5];
    const float* b_dt   = (const float*)d_in[6];
    const float* A_log  = (const float*)d_in[7];
    const float* Dvec   = (const float*)d_in[8];
    const float* W_out  = (const float*)d_in[9];
    float* out = (float*)d_out;

    const int BL = BATCH * SEQLEN;                    // 2048
    const size_t PS_ELEMS = (size_t)BATCH * NCHUNK * D_STATE * D_INNER; // 4,194,304

    // fp32 region
    float* ws     = (float*)d_ws;
    float* xz32   = ws;                                 // 4,194,304 (x_in half, fp32)
    float* x_dbl  = xz32   + (size_t)BL * D_INNER;      //   327,680
    float* Pst    = x_dbl  + (size_t)BL * XCOLS;        // 4,194,304
    float* Sst    = Pst    + PS_ELEMS;                  // 4,194,304
    float* Aneg   = Sst    + PS_ELEMS;                  // 32,768
    float* Cpart3 = Pst;     // 8 x 2048 x 256 = 4,194,304 (before phase1)
    float* Cpart6 = Pst;     // 2 x 2048 x 1024 = 4,194,304 (after phase3)
    bf16*  x_bf   = (bf16*)Sst;  // 2048x1024 bf16, dead before phase1
    // bf16 region
    bf16* Win_t  = (bf16*)(Aneg + 32768);               // 4096 x 1024
    bf16* u_bf   = Win_t + (size_t)4096 * 1024;         // 2048 x 2048
    bf16* Wxp_t  = u_bf  + (size_t)BL * D_INNER;        // 256  x 2048 (padded)
    bf16* dtA_bf = Wxp_t + (size_t)256 * 2048;          // 2048 x 128
    bf16* Wdt_t  = dtA_bf+ (size_t)BL * DT_RANK;        // 2048 x 128
    bf16* g_bf   = Wdt_t + (size_t)2048 * 128;          // 2048 x 2048
    bf16* Wout_t = g_bf  + (size_t)BL * D_INNER;        // 1024 x 2048
    bf16* dt_sb  = Wout_t+ (size_t)1024 * 2048;         // 2048 x 2048
    bf16* z_bf   = dt_sb + (size_t)BL * D_INNER;        // 2048 x 2048

    // 0) fused prep: 4 transposes + x convert + Aneg
    prep_kernel<<<4096 + 512 + 256 + 2048 + 2048 + 128, 256, 0, stream>>>(
        x, x_bf, W_in, Win_t, W_xproj, Wxp_t, W_dt, Wdt_t, W_out, Wout_t, A_log, Aneg);

    // 1) xz = x @ W_in; x_in half -> fp32 xz32, z half -> bf16 z_bf
    gemm_mfma<128, 2><<<dim3(32, 16, 1), 256, 0, stream>>>(
        x_bf, Win_t, xz32, z_bf, nullptr, BL, 2 * D_INNER, D_MODEL, D_INNER, D_MODEL);

    // 2) u_bf = bf16(silu(causal_conv(xz32) + b))
    conv_silu_kernel<<<(BL * D_INNER / 4) / 256, 256, 0, stream>>>(xz32, conv_k, conv_b, u_bf);

    // 3) x_dbl = u @ W_xproj  split-K 8, BN=64 -> 512 blocks
    gemm_mfma<64, 0><<<dim3(4, 16, 8), 256, 0, stream>>>(
        u_bf, Wxp_t, Cpart3, nullptr, nullptr, BL, 256, D_INNER, 256, 256);
    reduce_xdbl<<<(BL * XCOLS + 255) / 256, 256, 0, stream>>>(Cpart3, x_dbl, dtA_bf);

    // 4) dt_sb = bf16(softplus(dt_low @ W_dt + b_dt)), BN=64 -> 512 blocks
    gemm_mfma<64, 1><<<dim3(32, 16, 1), 256, 0, stream>>>(
        dtA_bf, Wdt_t, nullptr, dt_sb, b_dt, BL, D_INNER, DT_RANK, D_INNER, DT_RANK);

    // 5) chunked selective scan -> g_bf = bf16((y + u*D) * silu(z))
    scan_phase1<<<dim3(D_INNER / 128, NCHUNK, BATCH), 256, 0, stream>>>(
        dt_sb, Aneg, u_bf, x_dbl, Pst, Sst);
    scan_phase2<<<dim3(D_INNER / 256, D_STATE, BATCH), 256, 0, stream>>>(Pst, Sst);
    scan_phase3<<<dim3(D_INNER / 128, NCHUNK, BATCH), 256, 0, stream>>>(
        dt_sb, Aneg, u_bf, x_dbl, Dvec, z_bf, Sst, g_bf);

    // 6) out = g @ W_out  split-K 2, BN=64 -> 512 blocks
    gemm_mfma<64, 0><<<dim3(16, 16, 2), 256, 0, stream>>>(
        g_bf, Wout_t, Cpart6, nullptr, nullptr, BL, D_MODEL, D_INNER, D_MODEL, D_MODEL);
    reduce_out<<<(BL * D_MODEL / 4) / 256, 256, 0, stream>>>(Cpart6, out);
}